// Round 10
// baseline (96.247 us; speedup 1.0000x reference)
//
#include <hip/hip_runtime.h>
#include <math.h>

// AFM: B=4096, F=50, D=16, A=32, P=1225 pairs.
// out[b] = sum_p softmax_p( relu(inter_p @ W) . h ) * (inter_p . p_vec)
//
// Round 10: fire-and-forget phase 1 (R9 post-mortem: per-tile consumer chain
// MFMA->tree->shfl->exp2->update kept per-wave duty ~0.5-0.6; 333 issued
// cyc/tile vs ~130 floor).
//  - Phase 1: per tile, compute v (relu(z).h, log2 domain) and g, combine
//    K-halves with 2 store-terminal shfls, lanes<32 ds_write_b64 float2{v,g}.
//    No in-loop consumer => tiles pipeline across MFMA/LDS latency.
//  - Phase 2 (same wave, no barrier): stream 1248 float2s: e=exp2(v),
//    den+=e, num+=e*g. Pad/invalid slots stored v=-3e38 -> e=0.
//  - One wave = one batch: 512 thr, BPB=8, grid 512. LDS ~104 KB, 1 block/CU,
//    2 waves/SIMD (same TLP as R9 => delta isolates the chain restructure).
//  - MFMA mfma_f32_32x32x16_f16 (K=16), layouts validated R4-R9:
//    A[m=lane&31][k=(lane>>5)*8+jj], B[k][n=lane&31],
//    C/D row a=(reg&3)+8*(reg>>2)+4*(lane>>5), col n=lane&31.

#define FF 50
#define DD 16
#define AA 32
#define NP 1225
#define NT 39              // 32-pair tiles; tile 38 partial (9 valid)
#define NTP 40
#define ERS 24             // halves per e-row (48 B)
#define EBS (FF * ERS)     // 1200 halves per batch element
#define BPB 8              // batches per block = waves per block
#define NTHR 512
#define SGN (NT * 32)      // 1248 float2 slots per batch

typedef _Float16 half8 __attribute__((ext_vector_type(8)));
typedef _Float16 half4 __attribute__((ext_vector_type(4)));
typedef _Float16 half2v __attribute__((ext_vector_type(2)));
typedef __fp16   fh2    __attribute__((ext_vector_type(2)));
typedef float    floatx16 __attribute__((ext_vector_type(16)));

__global__ __launch_bounds__(NTHR, 2) void afm_kernel(
    const float* __restrict__ feat,   // [B, 50, 16]
    const float* __restrict__ W,      // [16, 32]
    const float* __restrict__ h,      // [32]
    const float* __restrict__ pvec,   // [16]
    float* __restrict__ out,          // [B]
    int Btot)
{
  __shared__ __align__(16) _Float16 eh[BPB * EBS];  // 19200 B
  __shared__ unsigned int tbl[NTP * 32];            // 5120 B
  __shared__ __align__(16) float2 sg[BPB * SGN];    // 79872 B

  const int tid    = threadIdx.x;
  const int lane   = tid & 63;
  const int wave   = tid >> 6;       // 0..7, owns batch b0+wave
  const int halfid = lane >> 5;
  const int n      = lane & 31;
  const int b0     = blockIdx.x * BPB;

  // ---- stage 8 batch elements -> f16 LDS ----
  for (int s = tid; s < BPB * 200; s += NTHR) {
    int bl  = s / 200;
    int rem = s - bl * 200;
    int bb  = b0 + bl;
    if (bb < Btot) {
      float4 v4 = ((const float4*)feat)[(size_t)bb * 200 + rem];
      half4 hv;
      hv[0] = (_Float16)v4.x; hv[1] = (_Float16)v4.y;
      hv[2] = (_Float16)v4.z; hv[3] = (_Float16)v4.w;
      int row = rem >> 2, q = rem & 3;
      *(half4*)(&eh[bl * EBS + row * ERS + q * 4]) = hv;
    }
  }

  // ---- interleaved pair table: dword q holds ent(t,nn),
  //      t=2*(q>>6)+(q&1), nn=(q>>1)&31; ent=(i*48)<<16|(j*48) ----
  for (int q = tid; q < NTP * 32; q += NTHR) {
    int t = ((q >> 6) << 1) | (q & 1);
    int nn = (q >> 1) & 31;
    int p = t * 32 + nn;
    unsigned ent = 0;
    if (p < NP) {
      int rad = 9801 - 8 * p;
      int i = (int)((99.0f - sqrtf((float)rad)) * 0.5f);
      if (i < 0) i = 0; if (i > 48) i = 48;
      int off = (i * (99 - i)) >> 1;
      if (off > p) { --i; off = (i * (99 - i)) >> 1; }
      else {
        int off1 = ((i + 1) * (98 - i)) >> 1;
        if (off1 <= p) { ++i; off = off1; }
      }
      int j = p - off + i + 1;
      ent = ((unsigned)(i * 48) << 16) | (unsigned)(j * 48);
    }
    tbl[q] = ent;
  }

  // ---- loop-invariant fragments ----
  const float LOG2E = 1.4426950408889634f;
  half8 A0;
  #pragma unroll
  for (int jj = 0; jj < 8; ++jj)
    A0[jj] = (_Float16)W[(halfid * 8 + jj) * AA + n];
  float hreg[16];
  #pragma unroll
  for (int r = 0; r < 16; ++r)
    hreg[r] = h[(r & 3) + 8 * (r >> 2) + 4 * halfid] * LOG2E;
  fh2 pv2[4];                         // pvec slice (f16) for this K-half
  #pragma unroll
  for (int q = 0; q < 4; ++q) {
    pv2[q][0] = (__fp16)pvec[halfid * 8 + 2 * q];
    pv2[q][1] = (__fp16)pvec[halfid * 8 + 2 * q + 1];
  }
  const floatx16 ZACC = (floatx16)0.0f;

  __syncthreads();

  // ---- phase 1: this wave's batch; store-terminal tiles ----
  const char* eb = (const char*)(eh + wave * EBS) + halfid * 16;
  float2* sgw = sg + wave * SGN;
  const unsigned int* tpair = tbl + 2 * n;

  auto core = [&](unsigned oi, unsigned oj, float& vout, float& gout) {
    half8 Bi = *(const half8*)(eb + oi);
    half8 Bj = *(const half8*)(eb + oj);
    half8 Bv = Bi * Bj;                       // 4x v_pk_mul_f16
    floatx16 z = __builtin_amdgcn_mfma_f32_32x32x16_f16(A0, Bv, ZACC, 0, 0, 0);
    float a0 = 0.f, a1 = 0.f, a2 = 0.f, a3 = 0.f;
    #pragma unroll
    for (int r = 0; r < 16; r += 4) {
      a0 = fmaf(fmaxf(z[r + 0], 0.f), hreg[r + 0], a0);
      a1 = fmaf(fmaxf(z[r + 1], 0.f), hreg[r + 1], a1);
      a2 = fmaf(fmaxf(z[r + 2], 0.f), hreg[r + 2], a2);
      a3 = fmaf(fmaxf(z[r + 3], 0.f), hreg[r + 3], a3);
    }
    float v = (a0 + a1) + (a2 + a3);
    // g partial via v_dot2_f32_f16 (register-renamed casts)
#if __has_builtin(__builtin_amdgcn_fdot2)
    fh2 q0 = __builtin_bit_cast(fh2, (half2v)__builtin_shufflevector(Bv, Bv, 0, 1));
    fh2 q1 = __builtin_bit_cast(fh2, (half2v)__builtin_shufflevector(Bv, Bv, 2, 3));
    fh2 q2 = __builtin_bit_cast(fh2, (half2v)__builtin_shufflevector(Bv, Bv, 4, 5));
    fh2 q3 = __builtin_bit_cast(fh2, (half2v)__builtin_shufflevector(Bv, Bv, 6, 7));
    float g = __builtin_amdgcn_fdot2(q1, pv2[1],
              __builtin_amdgcn_fdot2(q0, pv2[0], 0.f, false), false)
            + __builtin_amdgcn_fdot2(q3, pv2[3],
              __builtin_amdgcn_fdot2(q2, pv2[2], 0.f, false), false);
#else
    float g = 0.f;
    #pragma unroll
    for (int k = 0; k < 8; ++k)
      g = fmaf((float)Bv[k], (float)((const __fp16*)pv2)[k], g);
#endif
    // combine K-halves; both shfls are store-terminal (off the tile chain)
    vout = v + __shfl_xor(v, 32, 64);
    gout = g + __shfl_xor(g, 32, 64);
  };

  for (int th = 0; th < 19; ++th) {           // tiles 0..37, all valid
    uint2 ij2 = *(const uint2*)(tpair + th * 64);
    float v0, g0, v1, g1;
    core(ij2.x >> 16, ij2.x & 0xffffu, v0, g0);
    core(ij2.y >> 16, ij2.y & 0xffffu, v1, g1);
    if (lane < 32) {
      sgw[(2 * th)     * 32 + n] = make_float2(v0, g0);
      sgw[(2 * th + 1) * 32 + n] = make_float2(v1, g1);
    }
  }
  {                                           // peeled tile 38: valid n < 9
    unsigned ij = tpair[19 * 64];
    float v, g;
    core(ij >> 16, ij & 0xffffu, v, g);
    if (n >= 9) v = -3.0e38f;                 // pads -> exp2 = 0 in phase 2
    if (lane < 32) sgw[38 * 32 + n] = make_float2(v, g);
  }

  // ---- phase 2: stream this batch's 1248 slots (same wave, no barrier) ----
  float den = 0.f, num = 0.f;
  for (int p = lane; p < SGN; p += 64) {
    float2 s2 = sgw[p];
    float e = exp2f(s2.x);
    den += e;
    num = fmaf(e, s2.y, num);
  }
  #pragma unroll
  for (int mask = 32; mask >= 1; mask >>= 1) {
    den += __shfl_xor(den, mask, 64);
    num += __shfl_xor(num, mask, 64);
  }
  const int b = b0 + wave;
  if (lane == 0 && b < Btot) out[b] = num / den;
}

extern "C" void kernel_launch(void* const* d_in, const int* in_sizes, int n_in,
                              void* d_out, int out_size, void* d_ws, size_t ws_size,
                              hipStream_t stream) {
  const float* feat = (const float*)d_in[0];
  const float* W    = (const float*)d_in[1];
  const float* h    = (const float*)d_in[2];
  const float* pvec = (const float*)d_in[3];
  float* out = (float*)d_out;
  const int B = in_sizes[0] / (FF * DD);   // 4096
  afm_kernel<<<(B + BPB - 1) / BPB, NTHR, 0, stream>>>(feat, W, h, pvec, out, B);
}

// Round 11
// 86.022 us; speedup vs baseline: 1.1189x; 1.1189x over previous
//
#include <hip/hip_runtime.h>
#include <math.h>

// AFM: B=4096, F=50, D=16, A=32, P=1225 pairs.
// out[b] = sum_p softmax_p( relu(inter_p @ W) . h ) * (inter_p . p_vec)
//
// Round 11: TLP fix. Occupancy audit showed R9/R10 ran at only 2 waves/SIMD
// (grid 256/512 = 1 block/CU); per-wave duty ~0.5 (R8) was never covered.
//  - 256 thr/block, 1 batch per wave, BPB=4, grid 1024 -> 4 blocks/CU
//    co-resident = 16 waves/CU = 4 waves/SIMD. 4096 waves = 4096 batches.
//  - Fused R9 pipeline (R10's split-phase regressed; reverted).
//  - Raw __builtin_amdgcn_exp2f (no libm fixup); scores bounded in log2
//    domain (validated R7-R10).
//  - mfma_f32_32x32x16_f16 (K=16), layouts validated R4-R10:
//    A[m=lane&31][k=(lane>>5)*8+jj], B[k][n=lane&31],
//    C/D row a=(reg&3)+8*(reg>>2)+4*(lane>>5), col n=lane&31.
//  - g kept per-K-half, merged in the pure-add butterfly; out = 2*num/den.

#define FF 50
#define DD 16
#define AA 32
#define NP 1225
#define NT 39              // 32-pair tiles; tile 38 partial (9 valid)
#define NTP 40
#define ERS 24             // halves per e-row (48 B)
#define EBS (FF * ERS)     // 1200 halves per batch element
#define BPB 4              // batches per block = waves per block
#define NTHR 256

typedef _Float16 half8 __attribute__((ext_vector_type(8)));
typedef _Float16 half4 __attribute__((ext_vector_type(4)));
typedef _Float16 half2v __attribute__((ext_vector_type(2)));
typedef __fp16   fh2    __attribute__((ext_vector_type(2)));
typedef float    floatx16 __attribute__((ext_vector_type(16)));

__global__ __launch_bounds__(NTHR, 4) void afm_kernel(
    const float* __restrict__ feat,   // [B, 50, 16]
    const float* __restrict__ W,      // [16, 32]
    const float* __restrict__ h,      // [32]
    const float* __restrict__ pvec,   // [16]
    float* __restrict__ out,          // [B]
    int Btot)
{
  __shared__ __align__(16) _Float16 eh[BPB * EBS];  // 9600 B
  __shared__ unsigned int tbl[NTP * 32];            // 5120 B

  const int tid    = threadIdx.x;
  const int lane   = tid & 63;
  const int wave   = tid >> 6;       // 0..3, owns batch b0+wave
  const int halfid = lane >> 5;
  const int n      = lane & 31;
  const int b0     = blockIdx.x * BPB;

  // ---- stage 4 batch elements -> f16 LDS ----
  for (int s = tid; s < BPB * 200; s += NTHR) {
    int bl  = s / 200;
    int rem = s - bl * 200;
    int bb  = b0 + bl;
    if (bb < Btot) {
      float4 v4 = ((const float4*)feat)[(size_t)bb * 200 + rem];
      half4 hv;
      hv[0] = (_Float16)v4.x; hv[1] = (_Float16)v4.y;
      hv[2] = (_Float16)v4.z; hv[3] = (_Float16)v4.w;
      int row = rem >> 2, q = rem & 3;
      *(half4*)(&eh[bl * EBS + row * ERS + q * 4]) = hv;
    }
  }

  // ---- interleaved pair table: dword q holds ent(t,nn),
  //      t=2*(q>>6)+(q&1), nn=(q>>1)&31; ent=(i*48)<<16|(j*48) ----
  for (int q = tid; q < NTP * 32; q += NTHR) {
    int t = ((q >> 6) << 1) | (q & 1);
    int nn = (q >> 1) & 31;
    int p = t * 32 + nn;
    unsigned ent = 0;
    if (p < NP) {
      int rad = 9801 - 8 * p;
      int i = (int)((99.0f - sqrtf((float)rad)) * 0.5f);
      if (i < 0) i = 0; if (i > 48) i = 48;
      int off = (i * (99 - i)) >> 1;
      if (off > p) { --i; off = (i * (99 - i)) >> 1; }
      else {
        int off1 = ((i + 1) * (98 - i)) >> 1;
        if (off1 <= p) { ++i; off = off1; }
      }
      int j = p - off + i + 1;
      ent = ((unsigned)(i * 48) << 16) | (unsigned)(j * 48);
    }
    tbl[q] = ent;
  }

  // ---- loop-invariant fragments ----
  const float LOG2E = 1.4426950408889634f;
  half8 A0;
  #pragma unroll
  for (int jj = 0; jj < 8; ++jj)
    A0[jj] = (_Float16)W[(halfid * 8 + jj) * AA + n];
  float hreg[16];
  #pragma unroll
  for (int r = 0; r < 16; ++r)
    hreg[r] = h[(r & 3) + 8 * (r >> 2) + 4 * halfid] * LOG2E;
  fh2 pv2[4];                         // pvec slice (f16) for this K-half
  #pragma unroll
  for (int q = 0; q < 4; ++q) {
    pv2[q][0] = (__fp16)pvec[halfid * 8 + 2 * q];
    pv2[q][1] = (__fp16)pvec[halfid * 8 + 2 * q + 1];
  }
  const floatx16 ZACC = (floatx16)0.0f;

  __syncthreads();

  // ---- main loop: this wave owns batch b0+wave ----
  const char* eb = (const char*)(eh + wave * EBS) + halfid * 16;
  const unsigned int* tpair = tbl + 2 * n;

  // per-tile core: v full (shfl'd), g partial for this K-half
  auto core = [&](unsigned oi, unsigned oj, float& vout, float& gout) {
    half8 Bi = *(const half8*)(eb + oi);
    half8 Bj = *(const half8*)(eb + oj);
    half8 Bv = Bi * Bj;                       // 4x v_pk_mul_f16
    floatx16 z = __builtin_amdgcn_mfma_f32_32x32x16_f16(A0, Bv, ZACC, 0, 0, 0);
    float a0 = 0.f, a1 = 0.f, a2 = 0.f, a3 = 0.f;
    #pragma unroll
    for (int r = 0; r < 16; r += 4) {
      a0 = fmaf(fmaxf(z[r + 0], 0.f), hreg[r + 0], a0);
      a1 = fmaf(fmaxf(z[r + 1], 0.f), hreg[r + 1], a1);
      a2 = fmaf(fmaxf(z[r + 2], 0.f), hreg[r + 2], a2);
      a3 = fmaf(fmaxf(z[r + 3], 0.f), hreg[r + 3], a3);
    }
    float v = (a0 + a1) + (a2 + a3);
    vout = v + __shfl_xor(v, 32, 64);         // full score (log2 domain)
#if __has_builtin(__builtin_amdgcn_fdot2)
    fh2 q0 = __builtin_bit_cast(fh2, (half2v)__builtin_shufflevector(Bv, Bv, 0, 1));
    fh2 q1 = __builtin_bit_cast(fh2, (half2v)__builtin_shufflevector(Bv, Bv, 2, 3));
    fh2 q2 = __builtin_bit_cast(fh2, (half2v)__builtin_shufflevector(Bv, Bv, 4, 5));
    fh2 q3 = __builtin_bit_cast(fh2, (half2v)__builtin_shufflevector(Bv, Bv, 6, 7));
    gout = __builtin_amdgcn_fdot2(q1, pv2[1],
           __builtin_amdgcn_fdot2(q0, pv2[0], 0.f, false), false)
         + __builtin_amdgcn_fdot2(q3, pv2[3],
           __builtin_amdgcn_fdot2(q2, pv2[2], 0.f, false), false);
#else
    float gp = 0.f;
    #pragma unroll
    for (int k = 0; k < 8; ++k)
      gp = fmaf((float)Bv[k], (float)((const __fp16*)pv2)[k], gp);
    gout = gp;
#endif
  };

#if __has_builtin(__builtin_amdgcn_exp2f)
  #define EXP2(x) __builtin_amdgcn_exp2f(x)
#else
  #define EXP2(x) exp2f(x)
#endif

  float den = 0.f, num = 0.f;
  for (int th = 0; th < 19; ++th) {           // tiles 0..37, all valid
    uint2 ij2 = *(const uint2*)(tpair + th * 64);
    float v, g;
    core(ij2.x >> 16, ij2.x & 0xffffu, v, g);
    { float e = EXP2(v); den += e; num = fmaf(e, g, num); }
    core(ij2.y >> 16, ij2.y & 0xffffu, v, g);
    { float e = EXP2(v); den += e; num = fmaf(e, g, num); }
  }
  {                                           // peeled tile 38: valid n < 9
    unsigned ij = tpair[19 * 64];
    float v, g;
    core(ij >> 16, ij & 0xffffu, v, g);
    if (n >= 9) v = -3.0e38f;
    float e = EXP2(v); den += e; num = fmaf(e, g, num);
  }

  // ---- butterfly: pure adds (mask-32 merges g-halves; den double-counts) ----
  #pragma unroll
  for (int mask = 32; mask >= 1; mask >>= 1) {
    den += __shfl_xor(den, mask, 64);
    num += __shfl_xor(num, mask, 64);
  }
  const int b = b0 + wave;
  if (lane == 0 && b < Btot) out[b] = (2.0f * num) / den;
}

extern "C" void kernel_launch(void* const* d_in, const int* in_sizes, int n_in,
                              void* d_out, int out_size, void* d_ws, size_t ws_size,
                              hipStream_t stream) {
  const float* feat = (const float*)d_in[0];
  const float* W    = (const float*)d_in[1];
  const float* h    = (const float*)d_in[2];
  const float* pvec = (const float*)d_in[3];
  float* out = (float*)d_out;
  const int B = in_sizes[0] / (FF * DD);   // 4096
  afm_kernel<<<(B + BPB - 1) / BPB, NTHR, 0, stream>>>(feat, W, h, pvec, out, B);
}

// Round 12
// 81.687 us; speedup vs baseline: 1.1782x; 1.0531x over previous
//
#include <hip/hip_runtime.h>
#include <math.h>

// AFM: B=4096, F=50, D=16, A=32, P=1225 pairs.
// out[b] = sum_p softmax_p( relu(inter_p @ W) . h ) * (inter_p . p_vec)
//
// Round 12: (1) 8 independent accumulation streams per SIMD -- dual
// (den,num) register pairs per wave (even/odd tiles) x 4 waves/SIMD
// (512 thr, BPB=8, grid 512 = 2 blocks/CU); first time >4 streams/SIMD.
// (2) packed-f16 z-epilogue: 8x v_cvt_pkrtz + 8x v_pk_max_f16 +
// 8x v_dot2_f32_f16 replaces 16 fmax + 16 fma f32 (~11 fewer inst/tile).
//  - mfma_f32_32x32x16_f16 (K=16), layouts validated R4-R11:
//    A[m=lane&31][k=(lane>>5)*8+jj], B[k][n=lane&31],
//    C/D row a=(reg&3)+8*(reg>>2)+4*(lane>>5), col n=lane&31.
//  - No-max softmax in log2 domain (validated R7-R11).
//  - g kept per-K-half, merged in the pure-add butterfly; out = 2*num/den.

#define FF 50
#define DD 16
#define AA 32
#define NP 1225
#define NT 39              // 32-pair tiles; tile 38 partial (9 valid)
#define NTP 40
#define ERS 24             // halves per e-row (48 B)
#define EBS (FF * ERS)     // 1200 halves per batch element
#define BPB 8              // batches per block = waves per block
#define NTHR 512

typedef _Float16 half8 __attribute__((ext_vector_type(8)));
typedef _Float16 half4 __attribute__((ext_vector_type(4)));
typedef _Float16 half2v __attribute__((ext_vector_type(2)));
typedef __fp16   fh2    __attribute__((ext_vector_type(2)));
typedef float    floatx16 __attribute__((ext_vector_type(16)));

__global__ __launch_bounds__(NTHR, 4) void afm_kernel(
    const float* __restrict__ feat,   // [B, 50, 16]
    const float* __restrict__ W,      // [16, 32]
    const float* __restrict__ h,      // [32]
    const float* __restrict__ pvec,   // [16]
    float* __restrict__ out,          // [B]
    int Btot)
{
  __shared__ __align__(16) _Float16 eh[BPB * EBS];  // 19200 B
  __shared__ unsigned int tbl[NTP * 32];            // 5120 B

  const int tid    = threadIdx.x;
  const int lane   = tid & 63;
  const int wave   = tid >> 6;       // 0..7, owns batch b0+wave
  const int halfid = lane >> 5;
  const int n      = lane & 31;
  const int b0     = blockIdx.x * BPB;

  // ---- stage 8 batch elements -> f16 LDS ----
  for (int s = tid; s < BPB * 200; s += NTHR) {
    int bl  = s / 200;
    int rem = s - bl * 200;
    int bb  = b0 + bl;
    if (bb < Btot) {
      float4 v4 = ((const float4*)feat)[(size_t)bb * 200 + rem];
      half4 hv;
      hv[0] = (_Float16)v4.x; hv[1] = (_Float16)v4.y;
      hv[2] = (_Float16)v4.z; hv[3] = (_Float16)v4.w;
      int row = rem >> 2, q = rem & 3;
      *(half4*)(&eh[bl * EBS + row * ERS + q * 4]) = hv;
    }
  }

  // ---- interleaved pair table: dword q holds ent(t,nn),
  //      t=2*(q>>6)+(q&1), nn=(q>>1)&31; ent=(i*48)<<16|(j*48) ----
  for (int q = tid; q < NTP * 32; q += NTHR) {
    int t = ((q >> 6) << 1) | (q & 1);
    int nn = (q >> 1) & 31;
    int p = t * 32 + nn;
    unsigned ent = 0;
    if (p < NP) {
      int rad = 9801 - 8 * p;
      int i = (int)((99.0f - sqrtf((float)rad)) * 0.5f);
      if (i < 0) i = 0; if (i > 48) i = 48;
      int off = (i * (99 - i)) >> 1;
      if (off > p) { --i; off = (i * (99 - i)) >> 1; }
      else {
        int off1 = ((i + 1) * (98 - i)) >> 1;
        if (off1 <= p) { ++i; off = off1; }
      }
      int j = p - off + i + 1;
      ent = ((unsigned)(i * 48) << 16) | (unsigned)(j * 48);
    }
    tbl[q] = ent;
  }

  // ---- loop-invariant fragments ----
  const float LOG2E = 1.4426950408889634f;
  half8 A0;
  #pragma unroll
  for (int jj = 0; jj < 8; ++jj)
    A0[jj] = (_Float16)W[(halfid * 8 + jj) * AA + n];
  // h (f16, *log2e) paired to match C/D reg order: a(r)=(r&3)+8*(r>>2)+4*halfid
  fh2 h2[8];
  #pragma unroll
  for (int q = 0; q < 8; ++q) {
    h2[q][0] = (__fp16)(h[((2*q) & 3) + 8 * ((2*q) >> 2) + 4 * halfid] * LOG2E);
    h2[q][1] = (__fp16)(h[((2*q+1) & 3) + 8 * ((2*q+1) >> 2) + 4 * halfid] * LOG2E);
  }
  fh2 pv2[4];                         // pvec slice (f16) for this K-half
  #pragma unroll
  for (int q = 0; q < 4; ++q) {
    pv2[q][0] = (__fp16)pvec[halfid * 8 + 2 * q];
    pv2[q][1] = (__fp16)pvec[halfid * 8 + 2 * q + 1];
  }
  const floatx16 ZACC = (floatx16)0.0f;
  const fh2 zz = {(__fp16)0.f, (__fp16)0.f};

  __syncthreads();

  // ---- main loop: this wave owns batch b0+wave ----
  const char* eb = (const char*)(eh + wave * EBS) + halfid * 16;
  const unsigned int* tpair = tbl + 2 * n;

  // per-tile core: v full (shfl'd), g partial for this K-half
  auto core = [&](unsigned oi, unsigned oj, float& vout, float& gout) {
    half8 Bi = *(const half8*)(eb + oi);
    half8 Bj = *(const half8*)(eb + oj);
    half8 Bv = Bi * Bj;                       // 4x v_pk_mul_f16
    floatx16 z = __builtin_amdgcn_mfma_f32_32x32x16_f16(A0, Bv, ZACC, 0, 0, 0);
    // packed epilogue: cvt_pk -> pk_max(0) -> dot2 with h2
    float vL = 0.f, vH = 0.f;
    #pragma unroll
    for (int q = 0; q < 4; ++q) {
      fh2 zp = __builtin_amdgcn_cvt_pkrtz(z[2*q], z[2*q+1]);
      fh2 zr = __builtin_elementwise_max(zp, zz);       // v_pk_max_f16
      vL = __builtin_amdgcn_fdot2(zr, h2[q], vL, false);
    }
    #pragma unroll
    for (int q = 4; q < 8; ++q) {
      fh2 zp = __builtin_amdgcn_cvt_pkrtz(z[2*q], z[2*q+1]);
      fh2 zr = __builtin_elementwise_max(zp, zz);
      vH = __builtin_amdgcn_fdot2(zr, h2[q], vH, false);
    }
    float v = vL + vH;
    vout = v + __shfl_xor(v, 32, 64);         // full score (log2 domain)
    fh2 q0 = __builtin_bit_cast(fh2, (half2v)__builtin_shufflevector(Bv, Bv, 0, 1));
    fh2 q1 = __builtin_bit_cast(fh2, (half2v)__builtin_shufflevector(Bv, Bv, 2, 3));
    fh2 q2 = __builtin_bit_cast(fh2, (half2v)__builtin_shufflevector(Bv, Bv, 4, 5));
    fh2 q3 = __builtin_bit_cast(fh2, (half2v)__builtin_shufflevector(Bv, Bv, 6, 7));
    gout = __builtin_amdgcn_fdot2(q1, pv2[1],
           __builtin_amdgcn_fdot2(q0, pv2[0], 0.f, false), false)
         + __builtin_amdgcn_fdot2(q3, pv2[3],
           __builtin_amdgcn_fdot2(q2, pv2[2], 0.f, false), false);
  };

#if __has_builtin(__builtin_amdgcn_exp2f)
  #define EXP2(x) __builtin_amdgcn_exp2f(x)
#else
  #define EXP2(x) exp2f(x)
#endif

  // dual independent accumulation streams (even/odd tiles)
  float den0 = 0.f, num0 = 0.f, den1 = 0.f, num1 = 0.f;
  for (int th = 0; th < 19; ++th) {           // tiles 0..37, all valid
    uint2 ij2 = *(const uint2*)(tpair + th * 64);
    float v, g;
    core(ij2.x >> 16, ij2.x & 0xffffu, v, g);
    { float e = EXP2(v); den0 += e; num0 = fmaf(e, g, num0); }
    core(ij2.y >> 16, ij2.y & 0xffffu, v, g);
    { float e = EXP2(v); den1 += e; num1 = fmaf(e, g, num1); }
  }
  {                                           // peeled tile 38: valid n < 9
    unsigned ij = tpair[19 * 64];
    float v, g;
    core(ij >> 16, ij & 0xffffu, v, g);
    if (n >= 9) v = -3.0e38f;
    float e = EXP2(v); den0 += e; num0 = fmaf(e, g, num0);
  }
  float den = den0 + den1, num = num0 + num1;

  // ---- butterfly: pure adds (mask-32 merges g-halves; den double-counts) ----
  #pragma unroll
  for (int mask = 32; mask >= 1; mask >>= 1) {
    den += __shfl_xor(den, mask, 64);
    num += __shfl_xor(num, mask, 64);
  }
  const int b = b0 + wave;
  if (lane == 0 && b < Btot) out[b] = (2.0f * num) / den;
}

extern "C" void kernel_launch(void* const* d_in, const int* in_sizes, int n_in,
                              void* d_out, int out_size, void* d_ws, size_t ws_size,
                              hipStream_t stream) {
  const float* feat = (const float*)d_in[0];
  const float* W    = (const float*)d_in[1];
  const float* h    = (const float*)d_in[2];
  const float* pvec = (const float*)d_in[3];
  float* out = (float*)d_out;
  const int B = in_sizes[0] / (FF * DD);   // 4096
  afm_kernel<<<(B + BPB - 1) / BPB, NTHR, 0, stream>>>(feat, W, h, pvec, out, B);
}